// Round 5
// baseline (5045.428 us; speedup 1.0000x reference)
//
#include <hip/hip_runtime.h>

// LiquidNeuralNetwork: B=512, S=1024, IN=16, HID=64, OUT=1, N_SUB=4 (RK4).
// Latency-bound serial chain. Round-4 model (from r3 counters): VALUBusy 38%
// x ~320 cyc/eval = ~122 busy cyc = ~61 insts x 2cyc -> the wave issues at
// full rate but stalls ~60% on dep latency (tanh trans ops, DPP/permlane
// chains, fdot chains). Nothing left to issue within one chain.
// => TWO independent chains (batch rows b, b+256) per wave, interleaved in
// one instruction stream: chain B's instructions fill chain A's stall slots.
// Weight tables / discovery are lane-identical across chains (shared); only
// h/cr/xp/accumulators duplicate. Grid: 256 blocks x 64 threads.
// Expected ~150 cyc/eval (vs 320) -> ~1.5ms.
// (Round 5 = identical resubmit: round-4 bench died in infra, zero signal.)
//
// Structure per eval (per chain): split-4 dot (r3, verified): in-group DPP
// gather {^1,^2,^7,^8} -> 8 h2 regs; 32 fdot2 in 4 slots; butterfly combine
// permlane32_swap x2 + permlane16_swap x1. Discovery at setup (integer
// payloads) verifies gather order + swap modes + combine; mismatch falls
// back wave-uniformly to the 2-chain LDS-broadcast path.

constexpr int HID  = 64;
constexpr int INF  = 16;
constexpr int SLEN = 1024;

typedef __fp16 h2_t __attribute__((ext_vector_type(2)));
typedef unsigned u32x2_t __attribute__((ext_vector_type(2)));

template<int CTRL>
__device__ __forceinline__ unsigned dppmov(unsigned v) {
    return (unsigned)__builtin_amdgcn_update_dpp(0, (int)v, CTRL, 0xF, 0xF, true);
}

__device__ __forceinline__ float fdot(unsigned a, h2_t w, float acc) {
    return __builtin_amdgcn_fdot2(__builtin_bit_cast(h2_t, a), w, acc, false);
}

__device__ __forceinline__ float fast_tanh(float x) {
    // tanh(x) = 1 - 2/(e^{2x}+1); exact limits at +/-inf, no clamp needed.
    float e = __builtin_amdgcn_exp2f(x * 2.8853900817779268f); // 2*log2(e)
    float r = __builtin_amdgcn_rcpf(e + 1.0f);
    return fmaf(-2.0f, r, 1.0f);
}

// In-group all-gather: lane l ends with all 16 values of its 16-lane group
// as 8 h2 regs, lane-dependent order (discovered at setup).
__device__ __forceinline__ void gatherG(float t, unsigned g[8]) {
    unsigned th = (unsigned)__builtin_bit_cast(unsigned short, (__fp16)t);
    unsigned tp = dppmov<0xB1>(th);            // quad_perm [1,0,3,2] = ^1
    g[0] = (tp << 16) | th;                    // h2 {self, ^1}
    g[1] = dppmov<0x4E>(g[0]);                 // quad_perm [2,3,0,1] = ^2
    g[2] = dppmov<0x141>(g[0]);                // row_half_mirror = ^7
    g[3] = dppmov<0x141>(g[1]);
    g[4] = dppmov<0x128>(g[0]);                // row_ror:8 = ^8
    g[5] = dppmov<0x128>(g[1]);
    g[6] = dppmov<0x128>(g[2]);
    g[7] = dppmov<0x128>(g[3]);
}

__global__ __launch_bounds__(64, 1) void lnn_dual_kernel(
    const float* __restrict__ x,
    const float* __restrict__ W_in,
    const float* __restrict__ b_in,
    const float* __restrict__ W_hh,
    const float* __restrict__ W_ih,
    const float* __restrict__ bias,
    const float* __restrict__ tau,
    const float* __restrict__ W_out,
    const float* __restrict__ b_out,
    float* __restrict__ out)
{
    const int lane = threadIdx.x;        // hidden index (home of h_lane)
    const int bA   = blockIdx.x;         // chain A batch
    const int bB   = blockIdx.x + 256;   // chain B batch

    __shared__ __fp16 th_s[2][HID];      // fallback path only

    const float rtau = 1.0f / tau[lane];

    // --- shared setup: Wc = (W_ih @ W_in) row, cbase = folded bias ---------
    float Wc[INF];
    #pragma unroll
    for (int k = 0; k < INF; ++k) Wc[k] = 0.0f;
    float bcomb = 0.0f;
    for (int j = 0; j < HID; ++j) {
        float wij = W_ih[lane * HID + j];
        bcomb = fmaf(wij, b_in[j], bcomb);
        #pragma unroll
        for (int k = 0; k < INF; ++k) Wc[k] = fmaf(wij, W_in[j * INF + k], Wc[k]);
    }
    const float cbase = bcomb + bias[lane];
    const float bo    = b_out[0];

    const float hsub  = (1.0f / 1023.0f) * 0.25f;  // dt/N_SUB, dt = 1/1023
    const float hsubh = 0.5f * hsub;
    const float h6    = hsub * (1.0f / 6.0f);

    const float4* xrowA = (const float4*)(x + (size_t)bA * SLEN * INF);
    const float4* xrowB = (const float4*)(x + (size_t)bB * SLEN * INF);
    float* orowA = out + (size_t)bA * SLEN;
    float* orowB = out + (size_t)bB * SLEN;

    // per-step input projection from prefetched regs
    auto proj = [&](const float4& p0, const float4& p1,
                    const float4& p2, const float4& p3) -> float {
        float cA = fmaf(p0.x, Wc[0], fmaf(p0.y, Wc[1],
                   fmaf(p0.z, Wc[2], fmaf(p0.w, Wc[3], cbase))));
        float cB = fmaf(p1.x, Wc[4], fmaf(p1.y, Wc[5],
                   fmaf(p1.z, Wc[6], p1.w * Wc[7])));
        float cC = fmaf(p2.x, Wc[8], fmaf(p2.y, Wc[9],
                   fmaf(p2.z, Wc[10], p2.w * Wc[11])));
        float cD = fmaf(p3.x, Wc[12], fmaf(p3.y, Wc[13],
                   fmaf(p3.z, Wc[14], p3.w * Wc[15])));
        return ((cA + cB) + (cC + cD)) * rtau;
    };

    // --- discovery: in-group gather order + swap partner-slot modes --------
    unsigned gd[8];
    gatherG((float)lane, gd);            // payload = lane index, exact in f16
    int e0[8], e1[8];
    unsigned covm = 0;
    #pragma unroll
    for (int r = 0; r < 8; ++r) {
        h2_t pr = __builtin_bit_cast(h2_t, gd[r]);
        e0[r] = (((int)(float)pr[0]) & 15) | (lane & 48);  // forced in-group
        e1[r] = (((int)(float)pr[1]) & 15) | (lane & 48);
        covm |= 1u << (e0[r] & 15);
        covm |= 1u << (e1[r] & 15);
    }
    const bool gok = (__all(covm == 0xFFFFu) != 0);

    const bool hi32 = (lane & 32) != 0;
    const bool hi16 = (lane & 16) != 0;
    u32x2_t r32 = __builtin_amdgcn_permlane32_swap((unsigned)lane, (unsigned)lane, false, false);
    const bool m32A = (__all((int)(hi32 ? r32[0] : r32[1]) == (lane ^ 32)) != 0);
    const bool m32B = (__all((int)(hi32 ? r32[1] : r32[0]) == (lane ^ 32)) != 0);
    const bool ok32 = m32A || m32B;
    const bool p32_r0 = m32A ? hi32 : !hi32;   // per-lane: partner in r[0]?

    u32x2_t r16 = __builtin_amdgcn_permlane16_swap((unsigned)lane, (unsigned)lane, false, false);
    const bool m16A = (__all((int)(hi16 ? r16[0] : r16[1]) == (lane ^ 16)) != 0);
    const bool m16B = (__all((int)(hi16 ? r16[1] : r16[0]) == (lane ^ 16)) != 0);
    const bool ok16 = m16A || m16B;
    const bool p16_r0 = m16A ? hi16 : !hi16;

    auto partner32 = [&](float v) -> float {
        unsigned u = __builtin_bit_cast(unsigned, v);
        u32x2_t r = __builtin_amdgcn_permlane32_swap(u, u, false, false);
        return __builtin_bit_cast(float, p32_r0 ? r[0] : r[1]);
    };
    auto partner16 = [&](float v) -> float {
        unsigned u = __builtin_bit_cast(unsigned, v);
        u32x2_t r = __builtin_amdgcn_permlane16_swap(u, u, false, false);
        return __builtin_bit_cast(float, p16_r0 ? r[0] : r[1]);
    };
    auto comb4 = [&](float P0, float P1, float P2, float P3) -> float {
        float Q0 = P0 + partner32(P2);
        float Q1 = P1 + partner32(P3);
        return Q0 + partner16(Q1);
    };
    auto allsum4 = [&](float v) -> float {   // sum over the 4 group-partners
        float a = v + partner32(v);
        return a + partner16(a);
    };

    bool cok;
    {   // end-to-end combine self-test with exact integer payloads
        float P0 = (float)lane;
        float P1 = (float)lane + 64.0f;
        float P2 = (float)lane + 128.0f;
        float P3 = (float)lane + 192.0f;
        float got = comb4(P0, P1, P2, P3);
        float T = (float)lane + (float)(lane ^ 16) + (float)(lane ^ 32)
                + (float)(lane ^ 48) + 384.0f;
        cok = (__all(got == T) != 0);
    }

    const bool fastok = gok && ok32 && ok16 && cok;

    if (fastok) {
        // whp[k][r]: h2 of W_hh[o_k][e(r,*)] * rtau[o_k], o_k = lane^(k<<4)
        h2_t whp[4][8];
        #pragma unroll
        for (int k = 0; k < 4; ++k) {
            int o = lane ^ (k << 4);
            float rt = 1.0f / tau[o];
            const float* wrow = W_hh + o * HID;
            #pragma unroll
            for (int r = 0; r < 8; ++r) {
                whp[k][r] = __builtin_amdgcn_cvt_pkrtz(wrow[e0[r]] * rt,
                                                       wrow[e1[r]] * rt);
            }
        }
        h2_t wovp[8];                    // W_out over my group's elements
        #pragma unroll
        for (int r = 0; r < 8; ++r)
            wovp[r] = __builtin_amdgcn_cvt_pkrtz(W_out[e0[r]], W_out[e1[r]]);

        // split-4 partial dots for one chain (P[0] seeded with cmy)
        auto partials = [&](const unsigned g[8], float cmy, float P[4]) {
            #pragma unroll
            for (int k = 0; k < 4; ++k) {
                float u = (k == 0) ? cmy : 0.0f;
                float v = 0.0f;
                u = fdot(g[0], whp[k][0], u); v = fdot(g[1], whp[k][1], v);
                u = fdot(g[2], whp[k][2], u); v = fdot(g[3], whp[k][3], v);
                u = fdot(g[4], whp[k][4], u); v = fdot(g[5], whp[k][5], v);
                u = fdot(g[6], whp[k][6], u); v = fdot(g[7], whp[k][7], v);
                P[k] = u + v;
            }
        };
        auto odot = [&](const unsigned g[8]) -> float {
            float o0 = 0.f, o1 = 0.f;
            o0 = fdot(g[0], wovp[0], o0); o1 = fdot(g[1], wovp[1], o1);
            o0 = fdot(g[2], wovp[2], o0); o1 = fdot(g[3], wovp[3], o1);
            o0 = fdot(g[4], wovp[4], o0); o1 = fdot(g[5], wovp[5], o1);
            o0 = fdot(g[6], wovp[6], o0); o1 = fdot(g[7], wovp[7], o1);
            return o0 + o1;
        };

        // dual-chain eval: fills A's stall slots with B's instructions
        auto odef2 = [&](float yA, float yB, float crA, float crB,
                         float& fA, float& fB) {
            float cmyA = fmaf(-rtau, yA, crA);
            float cmyB = fmaf(-rtau, yB, crB);
            float tA = fast_tanh(yA);
            float tB = fast_tanh(yB);
            unsigned gA[8], gB[8];
            gatherG(tA, gA);
            gatherG(tB, gB);
            float PA[4], PB[4];
            partials(gA, cmyA, PA);
            partials(gB, cmyB, PB);
            fA = comb4(PA[0], PA[1], PA[2], PA[3]);
            fB = comb4(PB[0], PB[1], PB[2], PB[3]);
        };
        auto odef2_out = [&](float yA, float yB, float crA, float crB,
                             float& fA, float& fB, float& osA, float& osB) {
            float cmyA = fmaf(-rtau, yA, crA);
            float cmyB = fmaf(-rtau, yB, crB);
            float tA = fast_tanh(yA);
            float tB = fast_tanh(yB);
            unsigned gA[8], gB[8];
            gatherG(tA, gA);
            gatherG(tB, gB);
            float PA[4], PB[4];
            partials(gA, cmyA, PA);
            partials(gB, cmyB, PB);
            osA = allsum4(odot(gA));
            osB = allsum4(odot(gB));
            fA = comb4(PA[0], PA[1], PA[2], PA[3]);
            fB = comb4(PB[0], PB[1], PB[2], PB[3]);
        };

        float hA = 0.0f, hB = 0.0f;
        if (lane == 0) { orowA[0] = bo; orowB[0] = bo; }

        float4 xa0 = xrowA[4], xa1 = xrowA[5], xa2 = xrowA[6], xa3 = xrowA[7];
        float4 xb0 = xrowB[4], xb1 = xrowB[5], xb2 = xrowB[6], xb3 = xrowB[7];

        for (int s = 1; s < SLEN; ++s) {
            float crA = proj(xa0, xa1, xa2, xa3);
            float crB = proj(xb0, xb1, xb2, xb3);
            {   // prefetch next step's x (hidden behind the 16 evals below)
                int sn = (s < SLEN - 1) ? (s + 1) : (SLEN - 1);
                xa0 = xrowA[sn*4+0]; xa1 = xrowA[sn*4+1];
                xa2 = xrowA[sn*4+2]; xa3 = xrowA[sn*4+3];
                xb0 = xrowB[sn*4+0]; xb1 = xrowB[sn*4+1];
                xb2 = xrowB[sn*4+2]; xb3 = xrowB[sn*4+3];
            }
            {   // substep 0: first eval also yields previous step's outputs
                float k1A, k1B, osA, osB;
                odef2_out(hA, hB, crA, crB, k1A, k1B, osA, osB);
                if (lane == 0) { orowA[s-1] = osA + bo; orowB[s-1] = osB + bo; }
                float ksA = k1A, ksB = k1B;
                float k2A, k2B;
                odef2(fmaf(hsubh, k1A, hA), fmaf(hsubh, k1B, hB), crA, crB, k2A, k2B);
                ksA = fmaf(2.0f, k2A, ksA); ksB = fmaf(2.0f, k2B, ksB);
                float k3A, k3B;
                odef2(fmaf(hsubh, k2A, hA), fmaf(hsubh, k2B, hB), crA, crB, k3A, k3B);
                ksA = fmaf(2.0f, k3A, ksA); ksB = fmaf(2.0f, k3B, ksB);
                float k4A, k4B;
                odef2(fmaf(hsub, k3A, hA), fmaf(hsub, k3B, hB), crA, crB, k4A, k4B);
                ksA += k4A; ksB += k4B;
                hA = fmaf(h6, ksA, hA); hB = fmaf(h6, ksB, hB);
            }
            #pragma unroll
            for (int sub = 1; sub < 4; ++sub) {
                float k1A, k1B;
                odef2(hA, hB, crA, crB, k1A, k1B);
                float ksA = k1A, ksB = k1B;
                float k2A, k2B;
                odef2(fmaf(hsubh, k1A, hA), fmaf(hsubh, k1B, hB), crA, crB, k2A, k2B);
                ksA = fmaf(2.0f, k2A, ksA); ksB = fmaf(2.0f, k2B, ksB);
                float k3A, k3B;
                odef2(fmaf(hsubh, k2A, hA), fmaf(hsubh, k2B, hB), crA, crB, k3A, k3B);
                ksA = fmaf(2.0f, k3A, ksA); ksB = fmaf(2.0f, k3B, ksB);
                float k4A, k4B;
                odef2(fmaf(hsub, k3A, hA), fmaf(hsub, k3B, hB), crA, crB, k4A, k4B);
                ksA += k4A; ksB += k4B;
                hA = fmaf(h6, ksA, hA); hB = fmaf(h6, ksB, hB);
            }
        }
        {   // epilogue: out[1023] for both chains
            float tA = fast_tanh(hA);
            float tB = fast_tanh(hB);
            unsigned gA[8], gB[8];
            gatherG(tA, gA);
            gatherG(tB, gB);
            float oA = allsum4(odot(gA));
            float oB = allsum4(odot(gB));
            if (lane == 0) { orowA[SLEN-1] = oA + bo; orowB[SLEN-1] = oB + bo; }
        }
    } else {
        // ---- fallback: 2-chain LDS-broadcast path (verified structure) ----
        h2_t wh[HID / 2], wov[HID / 2];
        {
            const float4* w4 = (const float4*)(W_hh + lane * HID);
            const float4* o4 = (const float4*)(W_out);
            #pragma unroll
            for (int q = 0; q < HID / 4; ++q) {
                float4 v = w4[q];
                wh[2*q+0] = __builtin_amdgcn_cvt_pkrtz(v.x * rtau, v.y * rtau);
                wh[2*q+1] = __builtin_amdgcn_cvt_pkrtz(v.z * rtau, v.w * rtau);
                float4 o = o4[q];
                wov[2*q+0] = __builtin_amdgcn_cvt_pkrtz(o.x, o.y);
                wov[2*q+1] = __builtin_amdgcn_cvt_pkrtz(o.z, o.w);
            }
        }
        auto odef2 = [&](float yA, float yB, float crA, float crB,
                         float& fA, float& fB) {
            float cmyA = fmaf(-rtau, yA, crA);
            float cmyB = fmaf(-rtau, yB, crB);
            float tA = fast_tanh(yA);
            float tB = fast_tanh(yB);
            th_s[0][lane] = (__fp16)tA;
            th_s[1][lane] = (__fp16)tB;
            float aA0 = cmyA, aA1 = 0.f, aA2 = 0.f, aA3 = 0.f;
            float aB0 = cmyB, aB1 = 0.f, aB2 = 0.f, aB3 = 0.f;
            const uint4* tA4 = (const uint4*)th_s[0];
            const uint4* tB4 = (const uint4*)th_s[1];
            #pragma unroll
            for (int q = 0; q < 8; ++q) {
                uint4 ra = tA4[q];
                uint4 rb = tB4[q];
                aA0 = fdot(ra.x, wh[4*q+0], aA0);
                aA1 = fdot(ra.y, wh[4*q+1], aA1);
                aA2 = fdot(ra.z, wh[4*q+2], aA2);
                aA3 = fdot(ra.w, wh[4*q+3], aA3);
                aB0 = fdot(rb.x, wh[4*q+0], aB0);
                aB1 = fdot(rb.y, wh[4*q+1], aB1);
                aB2 = fdot(rb.z, wh[4*q+2], aB2);
                aB3 = fdot(rb.w, wh[4*q+3], aB3);
            }
            fA = (aA0 + aA1) + (aA2 + aA3);
            fB = (aB0 + aB1) + (aB2 + aB3);
        };
        auto odef2_out = [&](float yA, float yB, float crA, float crB,
                             float& fA, float& fB, float& osA, float& osB) {
            float cmyA = fmaf(-rtau, yA, crA);
            float cmyB = fmaf(-rtau, yB, crB);
            float tA = fast_tanh(yA);
            float tB = fast_tanh(yB);
            th_s[0][lane] = (__fp16)tA;
            th_s[1][lane] = (__fp16)tB;
            float aA0 = cmyA, aA1 = 0.f, aA2 = 0.f, aA3 = 0.f;
            float aB0 = cmyB, aB1 = 0.f, aB2 = 0.f, aB3 = 0.f;
            float oA0 = 0.f, oA1 = 0.f, oB0 = 0.f, oB1 = 0.f;
            const uint4* tA4 = (const uint4*)th_s[0];
            const uint4* tB4 = (const uint4*)th_s[1];
            #pragma unroll
            for (int q = 0; q < 8; ++q) {
                uint4 ra = tA4[q];
                uint4 rb = tB4[q];
                aA0 = fdot(ra.x, wh[4*q+0], aA0);
                aA1 = fdot(ra.y, wh[4*q+1], aA1);
                aA2 = fdot(ra.z, wh[4*q+2], aA2);
                aA3 = fdot(ra.w, wh[4*q+3], aA3);
                aB0 = fdot(rb.x, wh[4*q+0], aB0);
                aB1 = fdot(rb.y, wh[4*q+1], aB1);
                aB2 = fdot(rb.z, wh[4*q+2], aB2);
                aB3 = fdot(rb.w, wh[4*q+3], aB3);
                oA0 = fdot(ra.x, wov[4*q+0], oA0);
                oA1 = fdot(ra.y, wov[4*q+1], oA1);
                oA0 = fdot(ra.z, wov[4*q+2], oA0);
                oA1 = fdot(ra.w, wov[4*q+3], oA1);
                oB0 = fdot(rb.x, wov[4*q+0], oB0);
                oB1 = fdot(rb.y, wov[4*q+1], oB1);
                oB0 = fdot(rb.z, wov[4*q+2], oB0);
                oB1 = fdot(rb.w, wov[4*q+3], oB1);
            }
            fA = (aA0 + aA1) + (aA2 + aA3);
            fB = (aB0 + aB1) + (aB2 + aB3);
            osA = oA0 + oA1;
            osB = oB0 + oB1;
        };

        float hA = 0.0f, hB = 0.0f;
        if (lane == 0) { orowA[0] = bo; orowB[0] = bo; }

        float4 xa0 = xrowA[4], xa1 = xrowA[5], xa2 = xrowA[6], xa3 = xrowA[7];
        float4 xb0 = xrowB[4], xb1 = xrowB[5], xb2 = xrowB[6], xb3 = xrowB[7];

        for (int s = 1; s < SLEN; ++s) {
            float crA = proj(xa0, xa1, xa2, xa3);
            float crB = proj(xb0, xb1, xb2, xb3);
            {
                int sn = (s < SLEN - 1) ? (s + 1) : (SLEN - 1);
                xa0 = xrowA[sn*4+0]; xa1 = xrowA[sn*4+1];
                xa2 = xrowA[sn*4+2]; xa3 = xrowA[sn*4+3];
                xb0 = xrowB[sn*4+0]; xb1 = xrowB[sn*4+1];
                xb2 = xrowB[sn*4+2]; xb3 = xrowB[sn*4+3];
            }
            {
                float k1A, k1B, osA, osB;
                odef2_out(hA, hB, crA, crB, k1A, k1B, osA, osB);
                if (lane == 0) { orowA[s-1] = osA + bo; orowB[s-1] = osB + bo; }
                float ksA = k1A, ksB = k1B;
                float k2A, k2B;
                odef2(fmaf(hsubh, k1A, hA), fmaf(hsubh, k1B, hB), crA, crB, k2A, k2B);
                ksA = fmaf(2.0f, k2A, ksA); ksB = fmaf(2.0f, k2B, ksB);
                float k3A, k3B;
                odef2(fmaf(hsubh, k2A, hA), fmaf(hsubh, k2B, hB), crA, crB, k3A, k3B);
                ksA = fmaf(2.0f, k3A, ksA); ksB = fmaf(2.0f, k3B, ksB);
                float k4A, k4B;
                odef2(fmaf(hsub, k3A, hA), fmaf(hsub, k3B, hB), crA, crB, k4A, k4B);
                ksA += k4A; ksB += k4B;
                hA = fmaf(h6, ksA, hA); hB = fmaf(h6, ksB, hB);
            }
            #pragma unroll
            for (int sub = 1; sub < 4; ++sub) {
                float k1A, k1B;
                odef2(hA, hB, crA, crB, k1A, k1B);
                float ksA = k1A, ksB = k1B;
                float k2A, k2B;
                odef2(fmaf(hsubh, k1A, hA), fmaf(hsubh, k1B, hB), crA, crB, k2A, k2B);
                ksA = fmaf(2.0f, k2A, ksA); ksB = fmaf(2.0f, k2B, ksB);
                float k3A, k3B;
                odef2(fmaf(hsubh, k2A, hA), fmaf(hsubh, k2B, hB), crA, crB, k3A, k3B);
                ksA = fmaf(2.0f, k3A, ksA); ksB = fmaf(2.0f, k3B, ksB);
                float k4A, k4B;
                odef2(fmaf(hsub, k3A, hA), fmaf(hsub, k3B, hB), crA, crB, k4A, k4B);
                ksA += k4A; ksB += k4B;
                hA = fmaf(h6, ksA, hA); hB = fmaf(h6, ksB, hB);
            }
        }
        {   // epilogue
            float tA = fast_tanh(hA);
            float tB = fast_tanh(hB);
            th_s[0][lane] = (__fp16)tA;
            th_s[1][lane] = (__fp16)tB;
            float oA0 = 0.f, oA1 = 0.f, oB0 = 0.f, oB1 = 0.f;
            const uint4* tA4 = (const uint4*)th_s[0];
            const uint4* tB4 = (const uint4*)th_s[1];
            #pragma unroll
            for (int q = 0; q < 8; ++q) {
                uint4 ra = tA4[q];
                uint4 rb = tB4[q];
                oA0 = fdot(ra.x, wov[4*q+0], oA0);
                oA1 = fdot(ra.y, wov[4*q+1], oA1);
                oA0 = fdot(ra.z, wov[4*q+2], oA0);
                oA1 = fdot(ra.w, wov[4*q+3], oA1);
                oB0 = fdot(rb.x, wov[4*q+0], oB0);
                oB1 = fdot(rb.y, wov[4*q+1], oB1);
                oB0 = fdot(rb.z, wov[4*q+2], oB0);
                oB1 = fdot(rb.w, wov[4*q+3], oB1);
            }
            if (lane == 0) {
                orowA[SLEN-1] = oA0 + oA1 + bo;
                orowB[SLEN-1] = oB0 + oB1 + bo;
            }
        }
    }
}

extern "C" void kernel_launch(void* const* d_in, const int* in_sizes, int n_in,
                              void* d_out, int out_size, void* d_ws, size_t ws_size,
                              hipStream_t stream) {
    const float* x     = (const float*)d_in[0];
    const float* W_in  = (const float*)d_in[1];
    const float* b_in  = (const float*)d_in[2];
    const float* W_hh  = (const float*)d_in[3];
    const float* W_ih  = (const float*)d_in[4];
    const float* bias  = (const float*)d_in[5];
    const float* tau   = (const float*)d_in[6];
    const float* W_out = (const float*)d_in[7];
    const float* b_out = (const float*)d_in[8];
    float* out = (float*)d_out;

    lnn_dual_kernel<<<256, 64, 0, stream>>>(x, W_in, b_in, W_hh, W_ih, bias,
                                            tau, W_out, b_out, out);
}

// Round 7
// 3252.084 us; speedup vs baseline: 1.5514x; 1.5514x over previous
//
#include <hip/hip_runtime.h>

// LiquidNeuralNetwork: B=512, S=1024, IN=16, HID=64, OUT=1, N_SUB=4 (RK4).
// One chain per wave (512 blocks x 64 thr). r5 lesson: with 512 chains and
// 1024 SIMDs, wave count is NOT the constraint -- the wall is one chain's
// ~320-cyc/eval dependency chain (r3 counters: issue 122 cyc, rest stall).
//
// Round 7 = round 6 with the epilogue scope bug fixed (yhe was loop-local;
// epilogue now uses fast_tanh(h), identical semantics since yhe==E2L*h).
//  - ye/cmy chaining: exp2 input ye=2log2e*y and decay cmy=(c-y)*rtau are
//    each ONE fma from k_prev (yhe/cmyh rebuilt from h once per step);
//    y itself never materialized -> tanh pre-mul + y-fma off the chain.
//  - depth-2 fdot chains: 4 accumulators x 2 fdots per slot (was 2x4).
//  - split-4 dot + in-group DPP gather {^1,^2,^7,^8} + butterfly combine.
// Discovery (integer payloads) verifies gather order + swap modes + combine;
// mismatch falls back wave-uniformly to the verified LDS-broadcast path.

constexpr int HID  = 64;
constexpr int INF  = 16;
constexpr int SLEN = 1024;

constexpr float E2L = 2.8853900817779268f;   // 2*log2(e)

typedef __fp16 h2_t __attribute__((ext_vector_type(2)));
typedef unsigned u32x2_t __attribute__((ext_vector_type(2)));

template<int CTRL>
__device__ __forceinline__ unsigned dppmov(unsigned v) {
    return (unsigned)__builtin_amdgcn_update_dpp(0, (int)v, CTRL, 0xF, 0xF, true);
}

__device__ __forceinline__ float fdot(unsigned a, h2_t w, float acc) {
    return __builtin_amdgcn_fdot2(__builtin_bit_cast(h2_t, a), w, acc, false);
}

__device__ __forceinline__ float fast_tanh(float x) {
    // tanh(x) = 1 - 2/(e^{2x}+1); exact limits at +/-inf, no clamp needed.
    float e = __builtin_amdgcn_exp2f(x * E2L);
    float r = __builtin_amdgcn_rcpf(e + 1.0f);
    return fmaf(-2.0f, r, 1.0f);
}

// In-group all-gather: lane l ends with all 16 values of its 16-lane group
// as 8 h2 regs, lane-dependent order (discovered at setup).
__device__ __forceinline__ void gatherG(float t, unsigned g[8]) {
    unsigned th = (unsigned)__builtin_bit_cast(unsigned short, (__fp16)t);
    unsigned tp = dppmov<0xB1>(th);            // quad_perm [1,0,3,2] = ^1
    g[0] = (tp << 16) | th;                    // h2 {self, ^1} (v_lshl_or_b32)
    g[1] = dppmov<0x4E>(g[0]);                 // quad_perm [2,3,0,1] = ^2
    g[2] = dppmov<0x141>(g[0]);                // row_half_mirror = ^7
    g[3] = dppmov<0x141>(g[1]);
    g[4] = dppmov<0x128>(g[0]);                // row_ror:8 = ^8
    g[5] = dppmov<0x128>(g[1]);
    g[6] = dppmov<0x128>(g[2]);
    g[7] = dppmov<0x128>(g[3]);
}

__global__ __launch_bounds__(64, 1) void lnn_chain_kernel(
    const float* __restrict__ x,
    const float* __restrict__ W_in,
    const float* __restrict__ b_in,
    const float* __restrict__ W_hh,
    const float* __restrict__ W_ih,
    const float* __restrict__ bias,
    const float* __restrict__ tau,
    const float* __restrict__ W_out,
    const float* __restrict__ b_out,
    float* __restrict__ out)
{
    const int lane = threadIdx.x;        // hidden index (home of h_lane)
    const int b    = blockIdx.x;         // batch index

    __shared__ __fp16 th_s[HID];         // fallback path only

    const float rtau = 1.0f / tau[lane];

    // --- input-projection row: Wc = (W_ih @ W_in) row, cbase = folded bias ---
    float Wc[INF];
    #pragma unroll
    for (int k = 0; k < INF; ++k) Wc[k] = 0.0f;
    float bcomb = 0.0f;
    for (int j = 0; j < HID; ++j) {
        float wij = W_ih[lane * HID + j];
        bcomb = fmaf(wij, b_in[j], bcomb);
        #pragma unroll
        for (int k = 0; k < INF; ++k) Wc[k] = fmaf(wij, W_in[j * INF + k], Wc[k]);
    }
    const float cbase = bcomb + bias[lane];
    const float bo    = b_out[0];

    const float hsub  = (1.0f / 1023.0f) * 0.25f;  // dt/N_SUB, dt = 1/1023
    const float hsubh = 0.5f * hsub;
    const float h6    = hsub * (1.0f / 6.0f);

    // chain constants: ye = E2L*y, cmy = (c-y)*rtau, both 1 fma from k_prev
    const float e_hh  = E2L * hsubh;
    const float e_h   = E2L * hsub;
    const float e_h6  = E2L * h6;
    const float mr_hh = -rtau * hsubh;
    const float mr_h  = -rtau * hsub;
    const float mr_h6 = -rtau * h6;

    const float4* xrow = (const float4*)(x + (size_t)b * SLEN * INF);
    float* orow = out + (size_t)b * SLEN;

    auto proj = [&](const float4& p0, const float4& p1,
                    const float4& p2, const float4& p3) -> float {
        float cA = fmaf(p0.x, Wc[0], fmaf(p0.y, Wc[1],
                   fmaf(p0.z, Wc[2], fmaf(p0.w, Wc[3], cbase))));
        float cB = fmaf(p1.x, Wc[4], fmaf(p1.y, Wc[5],
                   fmaf(p1.z, Wc[6], p1.w * Wc[7])));
        float cC = fmaf(p2.x, Wc[8], fmaf(p2.y, Wc[9],
                   fmaf(p2.z, Wc[10], p2.w * Wc[11])));
        float cD = fmaf(p3.x, Wc[12], fmaf(p3.y, Wc[13],
                   fmaf(p3.z, Wc[14], p3.w * Wc[15])));
        return ((cA + cB) + (cC + cD)) * rtau;
    };

    // --- discovery: in-group gather order + swap partner-slot modes --------
    unsigned gd[8];
    gatherG((float)lane, gd);            // payload = lane index, exact in f16
    int e0[8], e1[8];
    unsigned covm = 0;
    #pragma unroll
    for (int r = 0; r < 8; ++r) {
        h2_t pr = __builtin_bit_cast(h2_t, gd[r]);
        e0[r] = (((int)(float)pr[0]) & 15) | (lane & 48);  // forced in-group
        e1[r] = (((int)(float)pr[1]) & 15) | (lane & 48);
        covm |= 1u << (e0[r] & 15);
        covm |= 1u << (e1[r] & 15);
    }
    const bool gok = (__all(covm == 0xFFFFu) != 0);

    const bool hi32 = (lane & 32) != 0;
    const bool hi16 = (lane & 16) != 0;
    u32x2_t r32 = __builtin_amdgcn_permlane32_swap((unsigned)lane, (unsigned)lane, false, false);
    const bool m32A = (__all((int)(hi32 ? r32[0] : r32[1]) == (lane ^ 32)) != 0);
    const bool m32B = (__all((int)(hi32 ? r32[1] : r32[0]) == (lane ^ 32)) != 0);
    const bool ok32 = m32A || m32B;
    const bool p32_r0 = m32A ? hi32 : !hi32;

    u32x2_t r16 = __builtin_amdgcn_permlane16_swap((unsigned)lane, (unsigned)lane, false, false);
    const bool m16A = (__all((int)(hi16 ? r16[0] : r16[1]) == (lane ^ 16)) != 0);
    const bool m16B = (__all((int)(hi16 ? r16[1] : r16[0]) == (lane ^ 16)) != 0);
    const bool ok16 = m16A || m16B;
    const bool p16_r0 = m16A ? hi16 : !hi16;

    auto partner32 = [&](float v) -> float {
        unsigned u = __builtin_bit_cast(unsigned, v);
        u32x2_t r = __builtin_amdgcn_permlane32_swap(u, u, false, false);
        return __builtin_bit_cast(float, p32_r0 ? r[0] : r[1]);
    };
    auto partner16 = [&](float v) -> float {
        unsigned u = __builtin_bit_cast(unsigned, v);
        u32x2_t r = __builtin_amdgcn_permlane16_swap(u, u, false, false);
        return __builtin_bit_cast(float, p16_r0 ? r[0] : r[1]);
    };
    auto comb4 = [&](float P0, float P1, float P2, float P3) -> float {
        float Q0 = P0 + partner32(P2);
        float Q1 = P1 + partner32(P3);
        return Q0 + partner16(Q1);
    };
    auto allsum4 = [&](float v) -> float {
        float a = v + partner32(v);
        return a + partner16(a);
    };

    bool cok;
    {   // end-to-end combine self-test with exact integer payloads
        float P0 = (float)lane;
        float P1 = (float)lane + 64.0f;
        float P2 = (float)lane + 128.0f;
        float P3 = (float)lane + 192.0f;
        float got = comb4(P0, P1, P2, P3);
        float T = (float)lane + (float)(lane ^ 16) + (float)(lane ^ 32)
                + (float)(lane ^ 48) + 384.0f;
        cok = (__all(got == T) != 0);
    }

    const bool fastok = gok && ok32 && ok16 && cok;

    if (fastok) {
        // whp[k][r]: h2 of W_hh[o_k][e(r,*)] * rtau[o_k], o_k = lane^(k<<4)
        h2_t whp[4][8];
        #pragma unroll
        for (int k = 0; k < 4; ++k) {
            int o = lane ^ (k << 4);
            float rt = 1.0f / tau[o];
            const float* wrow = W_hh + o * HID;
            #pragma unroll
            for (int r = 0; r < 8; ++r) {
                whp[k][r] = __builtin_amdgcn_cvt_pkrtz(wrow[e0[r]] * rt,
                                                       wrow[e1[r]] * rt);
            }
        }
        h2_t wovp[8];
        #pragma unroll
        for (int r = 0; r < 8; ++r)
            wovp[r] = __builtin_amdgcn_cvt_pkrtz(W_out[e0[r]], W_out[e1[r]]);

        // eval from chained ye (=E2L*y) and cmy (=(c-y)*rtau)
        auto evalF = [&](float ye, float cmy) -> float {
            float e = __builtin_amdgcn_exp2f(ye);
            float r = __builtin_amdgcn_rcpf(e + 1.0f);
            float t = fmaf(-2.0f, r, 1.0f);       // tanh(y)
            unsigned g[8];
            gatherG(t, g);
            float P[4];
            #pragma unroll
            for (int k = 0; k < 4; ++k) {         // 4 chains x depth 2
                float c0 = (k == 0) ? cmy : 0.0f;
                float c1 = 0.f, c2 = 0.f, c3 = 0.f;
                c0 = fdot(g[0], whp[k][0], c0); c1 = fdot(g[1], whp[k][1], c1);
                c2 = fdot(g[2], whp[k][2], c2); c3 = fdot(g[3], whp[k][3], c3);
                c0 = fdot(g[4], whp[k][4], c0); c1 = fdot(g[5], whp[k][5], c1);
                c2 = fdot(g[6], whp[k][6], c2); c3 = fdot(g[7], whp[k][7], c3);
                P[k] = (c0 + c1) + (c2 + c3);
            }
            return comb4(P[0], P[1], P[2], P[3]);
        };
        // same + output dot (previous step's os), off the h-critical path
        auto evalF_out = [&](float ye, float cmy, float& os) -> float {
            float e = __builtin_amdgcn_exp2f(ye);
            float r = __builtin_amdgcn_rcpf(e + 1.0f);
            float t = fmaf(-2.0f, r, 1.0f);
            unsigned g[8];
            gatherG(t, g);
            float P[4];
            #pragma unroll
            for (int k = 0; k < 4; ++k) {
                float c0 = (k == 0) ? cmy : 0.0f;
                float c1 = 0.f, c2 = 0.f, c3 = 0.f;
                c0 = fdot(g[0], whp[k][0], c0); c1 = fdot(g[1], whp[k][1], c1);
                c2 = fdot(g[2], whp[k][2], c2); c3 = fdot(g[3], whp[k][3], c3);
                c0 = fdot(g[4], whp[k][4], c0); c1 = fdot(g[5], whp[k][5], c1);
                c2 = fdot(g[6], whp[k][6], c2); c3 = fdot(g[7], whp[k][7], c3);
                P[k] = (c0 + c1) + (c2 + c3);
            }
            float o0 = 0.f, o1 = 0.f, o2 = 0.f, o3 = 0.f;
            o0 = fdot(g[0], wovp[0], o0); o1 = fdot(g[1], wovp[1], o1);
            o2 = fdot(g[2], wovp[2], o2); o3 = fdot(g[3], wovp[3], o3);
            o0 = fdot(g[4], wovp[4], o0); o1 = fdot(g[5], wovp[5], o1);
            o2 = fdot(g[6], wovp[6], o2); o3 = fdot(g[7], wovp[7], o3);
            os = allsum4((o0 + o1) + (o2 + o3));
            return comb4(P[0], P[1], P[2], P[3]);
        };

        float h = 0.0f;
        if (lane == 0) orow[0] = bo;     // dt=0 at s=0 -> h stays 0

        float4 xp0 = xrow[4], xp1 = xrow[5], xp2 = xrow[6], xp3 = xrow[7];

        for (int s = 1; s < SLEN; ++s) {
            float cr = proj(xp0, xp1, xp2, xp3);
            // per-step chain state (rebuilt from h -> no drift across steps)
            float yhe  = E2L * h;
            float cmyh = fmaf(-rtau, h, cr);
            {   // prefetch next step's x
                int sn = (s < SLEN - 1) ? (s + 1) : (SLEN - 1);
                xp0 = xrow[sn*4+0]; xp1 = xrow[sn*4+1];
                xp2 = xrow[sn*4+2]; xp3 = xrow[sn*4+3];
            }
            {   // substep 0: k1 eval also yields previous step's output
                float os;
                float k1 = evalF_out(yhe, cmyh, os);
                if (lane == 0) orow[s - 1] = os + bo;
                float ks = k1;
                float k2 = evalF(fmaf(e_hh, k1, yhe), fmaf(mr_hh, k1, cmyh));
                ks = fmaf(2.0f, k2, ks);
                float k3 = evalF(fmaf(e_hh, k2, yhe), fmaf(mr_hh, k2, cmyh));
                ks = fmaf(2.0f, k3, ks);
                float k4 = evalF(fmaf(e_h, k3, yhe), fmaf(mr_h, k3, cmyh));
                ks += k4;
                h    = fmaf(h6,    ks, h);
                yhe  = fmaf(e_h6,  ks, yhe);
                cmyh = fmaf(mr_h6, ks, cmyh);
            }
            #pragma unroll
            for (int sub = 1; sub < 4; ++sub) {
                float k1 = evalF(yhe, cmyh);
                float ks = k1;
                float k2 = evalF(fmaf(e_hh, k1, yhe), fmaf(mr_hh, k1, cmyh));
                ks = fmaf(2.0f, k2, ks);
                float k3 = evalF(fmaf(e_hh, k2, yhe), fmaf(mr_hh, k2, cmyh));
                ks = fmaf(2.0f, k3, ks);
                float k4 = evalF(fmaf(e_h, k3, yhe), fmaf(mr_h, k3, cmyh));
                ks += k4;
                h    = fmaf(h6,    ks, h);
                yhe  = fmaf(e_h6,  ks, yhe);
                cmyh = fmaf(mr_h6, ks, cmyh);
            }
        }
        {   // epilogue: out[1023] = wov . tanh(h_final) + bo  (h-based)
            float t = fast_tanh(h);
            unsigned g[8];
            gatherG(t, g);
            float o0 = 0.f, o1 = 0.f, o2 = 0.f, o3 = 0.f;
            o0 = fdot(g[0], wovp[0], o0); o1 = fdot(g[1], wovp[1], o1);
            o2 = fdot(g[2], wovp[2], o2); o3 = fdot(g[3], wovp[3], o3);
            o0 = fdot(g[4], wovp[4], o0); o1 = fdot(g[5], wovp[5], o1);
            o2 = fdot(g[6], wovp[6], o2); o3 = fdot(g[7], wovp[7], o3);
            float of = allsum4((o0 + o1) + (o2 + o3));
            if (lane == 0) orow[SLEN - 1] = of + bo;
        }
    } else {
        // ---- fallback: verified LDS-broadcast path (r0 structure) ---------
        h2_t wh[HID / 2], wov[HID / 2];
        {
            const float4* w4 = (const float4*)(W_hh + lane * HID);
            const float4* o4 = (const float4*)(W_out);
            #pragma unroll
            for (int q = 0; q < HID / 4; ++q) {
                float4 v = w4[q];
                wh[2*q+0] = __builtin_amdgcn_cvt_pkrtz(v.x * rtau, v.y * rtau);
                wh[2*q+1] = __builtin_amdgcn_cvt_pkrtz(v.z * rtau, v.w * rtau);
                float4 o = o4[q];
                wov[2*q+0] = __builtin_amdgcn_cvt_pkrtz(o.x, o.y);
                wov[2*q+1] = __builtin_amdgcn_cvt_pkrtz(o.z, o.w);
            }
        }
        auto odef = [&](float y, float cr) -> float {
            float cmy = fmaf(-rtau, y, cr);
            float t = fast_tanh(y);
            th_s[lane] = (__fp16)t;
            float a0 = cmy, a1 = 0.f, a2 = 0.f, a3 = 0.f;
            const uint4* t4 = (const uint4*)th_s;
            #pragma unroll
            for (int q = 0; q < 8; ++q) {
                uint4 r = t4[q];
                a0 = fdot(r.x, wh[4*q+0], a0);
                a1 = fdot(r.y, wh[4*q+1], a1);
                a2 = fdot(r.z, wh[4*q+2], a2);
                a3 = fdot(r.w, wh[4*q+3], a3);
            }
            return (a0 + a1) + (a2 + a3);
        };
        auto odef_out = [&](float y, float cr, float& os) -> float {
            float cmy = fmaf(-rtau, y, cr);
            float t = fast_tanh(y);
            th_s[lane] = (__fp16)t;
            float a0 = cmy, a1 = 0.f, a2 = 0.f, a3 = 0.f;
            float o0 = 0.f, o1 = 0.f, o2 = 0.f, o3 = 0.f;
            const uint4* t4 = (const uint4*)th_s;
            #pragma unroll
            for (int q = 0; q < 8; ++q) {
                uint4 r = t4[q];
                a0 = fdot(r.x, wh[4*q+0], a0);
                a1 = fdot(r.y, wh[4*q+1], a1);
                a2 = fdot(r.z, wh[4*q+2], a2);
                a3 = fdot(r.w, wh[4*q+3], a3);
                o0 = fdot(r.x, wov[4*q+0], o0);
                o1 = fdot(r.y, wov[4*q+1], o1);
                o2 = fdot(r.z, wov[4*q+2], o2);
                o3 = fdot(r.w, wov[4*q+3], o3);
            }
            os = (o0 + o1) + (o2 + o3);
            return (a0 + a1) + (a2 + a3);
        };

        float h = 0.0f;
        if (lane == 0) orow[0] = bo;
        float4 xp0 = xrow[4], xp1 = xrow[5], xp2 = xrow[6], xp3 = xrow[7];

        for (int s = 1; s < SLEN; ++s) {
            float cr = proj(xp0, xp1, xp2, xp3);
            {
                int sn = (s < SLEN - 1) ? (s + 1) : (SLEN - 1);
                xp0 = xrow[sn*4+0]; xp1 = xrow[sn*4+1];
                xp2 = xrow[sn*4+2]; xp3 = xrow[sn*4+3];
            }
            {
                float os;
                float k1 = odef_out(h, cr, os);
                if (lane == 0) orow[s - 1] = os + bo;
                float ks = k1;
                float k2 = odef(fmaf(hsubh, k1, h), cr); ks = fmaf(2.0f, k2, ks);
                float k3 = odef(fmaf(hsubh, k2, h), cr); ks = fmaf(2.0f, k3, ks);
                float k4 = odef(fmaf(hsub,  k3, h), cr); ks += k4;
                h = fmaf(h6, ks, h);
            }
            #pragma unroll
            for (int sub = 1; sub < 4; ++sub) {
                float k1 = odef(h, cr);
                float ks = k1;
                float k2 = odef(fmaf(hsubh, k1, h), cr); ks = fmaf(2.0f, k2, ks);
                float k3 = odef(fmaf(hsubh, k2, h), cr); ks = fmaf(2.0f, k3, ks);
                float k4 = odef(fmaf(hsub,  k3, h), cr); ks += k4;
                h = fmaf(h6, ks, h);
            }
        }
        {
            float t = fast_tanh(h);
            th_s[lane] = (__fp16)t;
            float o0 = 0.f, o1 = 0.f, o2 = 0.f, o3 = 0.f;
            const uint4* t4 = (const uint4*)th_s;
            #pragma unroll
            for (int q = 0; q < 8; ++q) {
                uint4 r = t4[q];
                o0 = fdot(r.x, wov[4*q+0], o0);
                o1 = fdot(r.y, wov[4*q+1], o1);
                o2 = fdot(r.z, wov[4*q+2], o2);
                o3 = fdot(r.w, wov[4*q+3], o3);
            }
            if (lane == 0) orow[SLEN - 1] = (o0 + o1) + (o2 + o3) + bo;
        }
    }
}

extern "C" void kernel_launch(void* const* d_in, const int* in_sizes, int n_in,
                              void* d_out, int out_size, void* d_ws, size_t ws_size,
                              hipStream_t stream) {
    const float* x     = (const float*)d_in[0];
    const float* W_in  = (const float*)d_in[1];
    const float* b_in  = (const float*)d_in[2];
    const float* W_hh  = (const float*)d_in[3];
    const float* W_ih  = (const float*)d_in[4];
    const float* bias  = (const float*)d_in[5];
    const float* tau   = (const float*)d_in[6];
    const float* W_out = (const float*)d_in[7];
    const float* b_out = (const float*)d_in[8];
    float* out = (float*)d_out;

    lnn_chain_kernel<<<512, 64, 0, stream>>>(x, W_in, b_in, W_hh, W_ih, bias,
                                             tau, W_out, b_out, out);
}

// Round 8
// 2742.274 us; speedup vs baseline: 1.8399x; 1.1859x over previous
//
#include <hip/hip_runtime.h>

// LiquidNeuralNetwork: B=512, S=1024, IN=16, HID=64, OUT=1, N_SUB=4 (RK4).
// One chain per wave (512 blocks x 64 thr). Empirical law from r0/r2/r3/r7:
// wall/eval ~= 4-5 cyc per instruction (issue-dominated at 1 wave/SIMD);
// r7's latency tricks added insts and regressed. So: r3 structure (best,
// 2851us) minus instructions.
//
// Round 8: cndmask-free butterfly combine. permlane{16,32}_swap(a,b) with
// DISTINCT operands returns both modified regs; r[0]+r[1] = a_l + b_{l^xor}
// or b_l + a_{l^xor} depending on convention -- argument order selects the
// needed pairing. comb4: 3 swaps + 3 adds (6 insts) vs 12 with cndmask.
// Both orders + the proven cndmask variant are compiled; an exact integer
// end-to-end test selects wave-uniformly at setup. LDS path = final fallback.

constexpr int HID  = 64;
constexpr int INF  = 16;
constexpr int SLEN = 1024;

typedef __fp16 h2_t __attribute__((ext_vector_type(2)));
typedef unsigned u32x2_t __attribute__((ext_vector_type(2)));

template<int CTRL>
__device__ __forceinline__ unsigned dppmov(unsigned v) {
    return (unsigned)__builtin_amdgcn_update_dpp(0, (int)v, CTRL, 0xF, 0xF, true);
}

__device__ __forceinline__ float fdot(unsigned a, h2_t w, float acc) {
    return __builtin_amdgcn_fdot2(__builtin_bit_cast(h2_t, a), w, acc, false);
}

__device__ __forceinline__ float fast_tanh(float x) {
    // tanh(x) = 1 - 2/(e^{2x}+1); exact limits at +/-inf, no clamp needed.
    float e = __builtin_amdgcn_exp2f(x * 2.8853900817779268f); // 2*log2(e)
    float r = __builtin_amdgcn_rcpf(e + 1.0f);
    return fmaf(-2.0f, r, 1.0f);
}

// In-group all-gather: lane l ends with all 16 values of its 16-lane group
// as 8 h2 regs, lane-dependent order (discovered at setup).
__device__ __forceinline__ void gatherG(float t, unsigned g[8]) {
    unsigned th = (unsigned)__builtin_bit_cast(unsigned short, (__fp16)t);
    unsigned tp = dppmov<0xB1>(th);            // quad_perm [1,0,3,2] = ^1
    g[0] = (tp << 16) | th;                    // h2 {self, ^1}
    g[1] = dppmov<0x4E>(g[0]);                 // quad_perm [2,3,0,1] = ^2
    g[2] = dppmov<0x141>(g[0]);                // row_half_mirror = ^7
    g[3] = dppmov<0x141>(g[1]);
    g[4] = dppmov<0x128>(g[0]);                // row_ror:8 = ^8
    g[5] = dppmov<0x128>(g[1]);
    g[6] = dppmov<0x128>(g[2]);
    g[7] = dppmov<0x128>(g[3]);
}

// pair swaps: returns both modified regs (float payloads)
__device__ __forceinline__ u32x2_t sw32(float a, float b) {
    return __builtin_amdgcn_permlane32_swap(__builtin_bit_cast(unsigned, a),
                                            __builtin_bit_cast(unsigned, b),
                                            false, false);
}
__device__ __forceinline__ u32x2_t sw16(float a, float b) {
    return __builtin_amdgcn_permlane16_swap(__builtin_bit_cast(unsigned, a),
                                            __builtin_bit_cast(unsigned, b),
                                            false, false);
}
__device__ __forceinline__ float sum2(u32x2_t r) {
    return __builtin_bit_cast(float, r[0]) + __builtin_bit_cast(float, r[1]);
}

__global__ __launch_bounds__(64, 1) void lnn_swap_kernel(
    const float* __restrict__ x,
    const float* __restrict__ W_in,
    const float* __restrict__ b_in,
    const float* __restrict__ W_hh,
    const float* __restrict__ W_ih,
    const float* __restrict__ bias,
    const float* __restrict__ tau,
    const float* __restrict__ W_out,
    const float* __restrict__ b_out,
    float* __restrict__ out)
{
    const int lane = threadIdx.x;        // hidden index (home of h_lane)
    const int b    = blockIdx.x;         // batch index

    __shared__ __fp16 th_s[HID];         // fallback path only

    const float rtau = 1.0f / tau[lane];

    // --- input-projection row: Wc = (W_ih @ W_in) row, cbase = folded bias ---
    float Wc[INF];
    #pragma unroll
    for (int k = 0; k < INF; ++k) Wc[k] = 0.0f;
    float bcomb = 0.0f;
    for (int j = 0; j < HID; ++j) {
        float wij = W_ih[lane * HID + j];
        bcomb = fmaf(wij, b_in[j], bcomb);
        #pragma unroll
        for (int k = 0; k < INF; ++k) Wc[k] = fmaf(wij, W_in[j * INF + k], Wc[k]);
    }
    const float cbase = bcomb + bias[lane];
    const float bo    = b_out[0];

    float cr = 0.0f;                     // c_step * rtau (written in the loop)

    const float hsub  = (1.0f / 1023.0f) * 0.25f;  // dt/N_SUB, dt = 1/1023
    const float hsubh = 0.5f * hsub;
    const float h6    = hsub * (1.0f / 6.0f);

    const float4* xrow = (const float4*)(x + (size_t)b * SLEN * INF);
    float* orow = out + (size_t)b * SLEN;

    auto proj = [&](const float4& p0, const float4& p1,
                    const float4& p2, const float4& p3) -> float {
        float cA = fmaf(p0.x, Wc[0], fmaf(p0.y, Wc[1],
                   fmaf(p0.z, Wc[2], fmaf(p0.w, Wc[3], cbase))));
        float cB = fmaf(p1.x, Wc[4], fmaf(p1.y, Wc[5],
                   fmaf(p1.z, Wc[6], p1.w * Wc[7])));
        float cC = fmaf(p2.x, Wc[8], fmaf(p2.y, Wc[9],
                   fmaf(p2.z, Wc[10], p2.w * Wc[11])));
        float cD = fmaf(p3.x, Wc[12], fmaf(p3.y, Wc[13],
                   fmaf(p3.z, Wc[14], p3.w * Wc[15])));
        return ((cA + cB) + (cC + cD)) * rtau;
    };

    // --- discovery: in-group gather order -----------------------------------
    unsigned gd[8];
    gatherG((float)lane, gd);            // payload = lane index, exact in f16
    int e0[8], e1[8];
    unsigned covm = 0;
    #pragma unroll
    for (int r = 0; r < 8; ++r) {
        h2_t pr = __builtin_bit_cast(h2_t, gd[r]);
        e0[r] = (((int)(float)pr[0]) & 15) | (lane & 48);  // forced in-group
        e1[r] = (((int)(float)pr[1]) & 15) | (lane & 48);
        covm |= 1u << (e0[r] & 15);
        covm |= 1u << (e1[r] & 15);
    }
    const bool gok = (__all(covm == 0xFFFFu) != 0);

    // --- M0 (proven r3) combine machinery: partner via cndmask -------------
    const bool hi32 = (lane & 32) != 0;
    const bool hi16 = (lane & 16) != 0;
    u32x2_t r32 = __builtin_amdgcn_permlane32_swap((unsigned)lane, (unsigned)lane, false, false);
    const bool m32A = (__all((int)(hi32 ? r32[0] : r32[1]) == (lane ^ 32)) != 0);
    const bool m32B = (__all((int)(hi32 ? r32[1] : r32[0]) == (lane ^ 32)) != 0);
    const bool ok32 = m32A || m32B;
    const bool p32_r0 = m32A ? hi32 : !hi32;

    u32x2_t r16 = __builtin_amdgcn_permlane16_swap((unsigned)lane, (unsigned)lane, false, false);
    const bool m16A = (__all((int)(hi16 ? r16[0] : r16[1]) == (lane ^ 16)) != 0);
    const bool m16B = (__all((int)(hi16 ? r16[1] : r16[0]) == (lane ^ 16)) != 0);
    const bool ok16 = m16A || m16B;
    const bool p16_r0 = m16A ? hi16 : !hi16;

    auto partner32 = [&](float v) -> float {
        unsigned u = __builtin_bit_cast(unsigned, v);
        u32x2_t r = __builtin_amdgcn_permlane32_swap(u, u, false, false);
        return __builtin_bit_cast(float, p32_r0 ? r[0] : r[1]);
    };
    auto partner16 = [&](float v) -> float {
        unsigned u = __builtin_bit_cast(unsigned, v);
        u32x2_t r = __builtin_amdgcn_permlane16_swap(u, u, false, false);
        return __builtin_bit_cast(float, p16_r0 ? r[0] : r[1]);
    };
    auto comb4_m0 = [&](float P0, float P1, float P2, float P3) -> float {
        float Q0 = P0 + partner32(P2);
        float Q1 = P1 + partner32(P3);
        return Q0 + partner16(Q1);
    };
    auto allsum_m0 = [&](float v) -> float {
        float a = v + partner32(v);
        return a + partner16(a);
    };

    // --- M1/M2: cndmask-free combine via two-operand swap + add ------------
    // M1 assumes sum2(sw(a,b)) = a_l + b_{l^x}; M2 assumes = b_l + a_{l^x}.
    auto comb4_m1 = [&](float P0, float P1, float P2, float P3) -> float {
        float Q0 = sum2(sw32(P0, P2));
        float Q1 = sum2(sw32(P1, P3));
        return sum2(sw16(Q0, Q1));
    };
    auto comb4_m2 = [&](float P0, float P1, float P2, float P3) -> float {
        float Q0 = sum2(sw32(P2, P0));
        float Q1 = sum2(sw32(P3, P1));
        return sum2(sw16(Q1, Q0));
    };
    auto allsum_m12 = [&](float v) -> float {   // self+partner: order-agnostic
        float a = sum2(sw32(v, v));
        return sum2(sw16(a, a));
    };

    // --- end-to-end integer-payload tests (exact in f32) -------------------
    auto ctest = [&](auto&& cf) -> bool {
        float P0 = (float)lane;
        float P1 = (float)lane + 64.0f;
        float P2 = (float)lane + 128.0f;
        float P3 = (float)lane + 192.0f;
        float T  = (float)lane + (float)(lane ^ 16) + (float)(lane ^ 32)
                 + (float)(lane ^ 48) + 384.0f;
        return __all(cf(P0, P1, P2, P3) == T) != 0;
    };
    auto atest = [&](auto&& af) -> bool {
        float T = (float)lane + (float)(lane ^ 16) + (float)(lane ^ 32)
                + (float)(lane ^ 48);
        return __all(af((float)lane) == T) != 0;
    };

    const bool v1 = ctest(comb4_m1) && atest(allsum_m12);
    const bool v2 = ctest(comb4_m2) && atest(allsum_m12);
    const bool v0 = ok32 && ok16 && ctest(comb4_m0) && atest(allsum_m0);

    if (gok && (v1 || v2 || v0)) {
        // whp[k][r]: h2 of W_hh[o_k][e(r,*)] * rtau[o_k], o_k = lane^(k<<4)
        h2_t whp[4][8];
        #pragma unroll
        for (int k = 0; k < 4; ++k) {
            int o = lane ^ (k << 4);
            float rt = 1.0f / tau[o];
            const float* wrow = W_hh + o * HID;
            #pragma unroll
            for (int r = 0; r < 8; ++r) {
                whp[k][r] = __builtin_amdgcn_cvt_pkrtz(wrow[e0[r]] * rt,
                                                       wrow[e1[r]] * rt);
            }
        }
        h2_t wovp[8];                    // W_out over my group's elements
        #pragma unroll
        for (int r = 0; r < 8; ++r)
            wovp[r] = __builtin_amdgcn_cvt_pkrtz(W_out[e0[r]], W_out[e1[r]]);

        // generic fast chain, parameterized on combine/allsum implementation
        auto runfast = [&](auto&& C4, auto&& AS) {
            auto odef = [&](float y) -> float {
                float cmy = fmaf(-rtau, y, cr);
                float t = fast_tanh(y);
                unsigned g[8];
                gatherG(t, g);
                float P[4];
                #pragma unroll
                for (int k = 0; k < 4; ++k) {     // 2 chains x depth 4 (r3)
                    float u = (k == 0) ? cmy : 0.0f;
                    float v = 0.0f;
                    u = fdot(g[0], whp[k][0], u); v = fdot(g[1], whp[k][1], v);
                    u = fdot(g[2], whp[k][2], u); v = fdot(g[3], whp[k][3], v);
                    u = fdot(g[4], whp[k][4], u); v = fdot(g[5], whp[k][5], v);
                    u = fdot(g[6], whp[k][6], u); v = fdot(g[7], whp[k][7], v);
                    P[k] = u + v;
                }
                return C4(P[0], P[1], P[2], P[3]);
            };
            auto odef_out = [&](float y, float& os) -> float {
                float cmy = fmaf(-rtau, y, cr);
                float t = fast_tanh(y);
                unsigned g[8];
                gatherG(t, g);
                float P[4];
                #pragma unroll
                for (int k = 0; k < 4; ++k) {
                    float u = (k == 0) ? cmy : 0.0f;
                    float v = 0.0f;
                    u = fdot(g[0], whp[k][0], u); v = fdot(g[1], whp[k][1], v);
                    u = fdot(g[2], whp[k][2], u); v = fdot(g[3], whp[k][3], v);
                    u = fdot(g[4], whp[k][4], u); v = fdot(g[5], whp[k][5], v);
                    u = fdot(g[6], whp[k][6], u); v = fdot(g[7], whp[k][7], v);
                    P[k] = u + v;
                }
                float o0 = 0.f, o1 = 0.f;
                o0 = fdot(g[0], wovp[0], o0); o1 = fdot(g[1], wovp[1], o1);
                o0 = fdot(g[2], wovp[2], o0); o1 = fdot(g[3], wovp[3], o1);
                o0 = fdot(g[4], wovp[4], o0); o1 = fdot(g[5], wovp[5], o1);
                o0 = fdot(g[6], wovp[6], o0); o1 = fdot(g[7], wovp[7], o1);
                os = AS(o0 + o1);
                return C4(P[0], P[1], P[2], P[3]);
            };

            float h = 0.0f;
            if (lane == 0) orow[0] = bo;     // dt=0 at s=0 -> h stays 0
            float4 xp0 = xrow[4], xp1 = xrow[5], xp2 = xrow[6], xp3 = xrow[7];

            for (int s = 1; s < SLEN; ++s) {
                cr = proj(xp0, xp1, xp2, xp3);
                {   // prefetch next step's x
                    int sn = (s < SLEN - 1) ? (s + 1) : (SLEN - 1);
                    xp0 = xrow[sn*4+0]; xp1 = xrow[sn*4+1];
                    xp2 = xrow[sn*4+2]; xp3 = xrow[sn*4+3];
                }
                {   // substep 0: first eval also yields previous step's output
                    float os;
                    float k1 = odef_out(h, os);
                    if (lane == 0) orow[s - 1] = os + bo;
                    float ks = k1;
                    float k2 = odef(fmaf(hsubh, k1, h)); ks = fmaf(2.0f, k2, ks);
                    float k3 = odef(fmaf(hsubh, k2, h)); ks = fmaf(2.0f, k3, ks);
                    float k4 = odef(fmaf(hsub,  k3, h)); ks += k4;
                    h = fmaf(h6, ks, h);
                }
                #pragma unroll
                for (int sub = 1; sub < 4; ++sub) {
                    float k1 = odef(h);
                    float ks = k1;
                    float k2 = odef(fmaf(hsubh, k1, h)); ks = fmaf(2.0f, k2, ks);
                    float k3 = odef(fmaf(hsubh, k2, h)); ks = fmaf(2.0f, k3, ks);
                    float k4 = odef(fmaf(hsub,  k3, h)); ks += k4;
                    h = fmaf(h6, ks, h);
                }
            }
            {   // epilogue: out[1023] = wov . tanh(h_final) + bo
                float t = fast_tanh(h);
                unsigned g[8];
                gatherG(t, g);
                float o0 = 0.f, o1 = 0.f;
                o0 = fdot(g[0], wovp[0], o0); o1 = fdot(g[1], wovp[1], o1);
                o0 = fdot(g[2], wovp[2], o0); o1 = fdot(g[3], wovp[3], o1);
                o0 = fdot(g[4], wovp[4], o0); o1 = fdot(g[5], wovp[5], o1);
                o0 = fdot(g[6], wovp[6], o0); o1 = fdot(g[7], wovp[7], o1);
                float of = AS(o0 + o1);
                if (lane == 0) orow[SLEN - 1] = of + bo;
            }
        };

        if (v1)      runfast(comb4_m1, allsum_m12);
        else if (v2) runfast(comb4_m2, allsum_m12);
        else         runfast(comb4_m0, allsum_m0);
    } else {
        // ---- fallback: verified LDS-broadcast path (r0 structure) ---------
        h2_t wh[HID / 2], wov[HID / 2];
        {
            const float4* w4 = (const float4*)(W_hh + lane * HID);
            const float4* o4 = (const float4*)(W_out);
            #pragma unroll
            for (int q = 0; q < HID / 4; ++q) {
                float4 v = w4[q];
                wh[2*q+0] = __builtin_amdgcn_cvt_pkrtz(v.x * rtau, v.y * rtau);
                wh[2*q+1] = __builtin_amdgcn_cvt_pkrtz(v.z * rtau, v.w * rtau);
                float4 o = o4[q];
                wov[2*q+0] = __builtin_amdgcn_cvt_pkrtz(o.x, o.y);
                wov[2*q+1] = __builtin_amdgcn_cvt_pkrtz(o.z, o.w);
            }
        }
        auto odef = [&](float y) -> float {
            float cmy = fmaf(-rtau, y, cr);
            float t = fast_tanh(y);
            th_s[lane] = (__fp16)t;
            float a0 = cmy, a1 = 0.f, a2 = 0.f, a3 = 0.f;
            const uint4* t4 = (const uint4*)th_s;
            #pragma unroll
            for (int q = 0; q < 8; ++q) {
                uint4 r = t4[q];
                a0 = fdot(r.x, wh[4*q+0], a0);
                a1 = fdot(r.y, wh[4*q+1], a1);
                a2 = fdot(r.z, wh[4*q+2], a2);
                a3 = fdot(r.w, wh[4*q+3], a3);
            }
            return (a0 + a1) + (a2 + a3);
        };
        auto odef_out = [&](float y, float& os) -> float {
            float cmy = fmaf(-rtau, y, cr);
            float t = fast_tanh(y);
            th_s[lane] = (__fp16)t;
            float a0 = cmy, a1 = 0.f, a2 = 0.f, a3 = 0.f;
            float o0 = 0.f, o1 = 0.f, o2 = 0.f, o3 = 0.f;
            const uint4* t4 = (const uint4*)th_s;
            #pragma unroll
            for (int q = 0; q < 8; ++q) {
                uint4 r = t4[q];
                a0 = fdot(r.x, wh[4*q+0], a0);
                a1 = fdot(r.y, wh[4*q+1], a1);
                a2 = fdot(r.z, wh[4*q+2], a2);
                a3 = fdot(r.w, wh[4*q+3], a3);
                o0 = fdot(r.x, wov[4*q+0], o0);
                o1 = fdot(r.y, wov[4*q+1], o1);
                o2 = fdot(r.z, wov[4*q+2], o2);
                o3 = fdot(r.w, wov[4*q+3], o3);
            }
            os = (o0 + o1) + (o2 + o3);
            return (a0 + a1) + (a2 + a3);
        };

        float h = 0.0f;
        if (lane == 0) orow[0] = bo;
        float4 xp0 = xrow[4], xp1 = xrow[5], xp2 = xrow[6], xp3 = xrow[7];

        for (int s = 1; s < SLEN; ++s) {
            cr = proj(xp0, xp1, xp2, xp3);
            {
                int sn = (s < SLEN - 1) ? (s + 1) : (SLEN - 1);
                xp0 = xrow[sn*4+0]; xp1 = xrow[sn*4+1];
                xp2 = xrow[sn*4+2]; xp3 = xrow[sn*4+3];
            }
            {
                float os;
                float k1 = odef_out(h, os);
                if (lane == 0) orow[s - 1] = os + bo;
                float ks = k1;
                float k2 = odef(fmaf(hsubh, k1, h)); ks = fmaf(2.0f, k2, ks);
                float k3 = odef(fmaf(hsubh, k2, h)); ks = fmaf(2.0f, k3, ks);
                float k4 = odef(fmaf(hsub,  k3, h)); ks += k4;
                h = fmaf(h6, ks, h);
            }
            #pragma unroll
            for (int sub = 1; sub < 4; ++sub) {
                float k1 = odef(h);
                float ks = k1;
                float k2 = odef(fmaf(hsubh, k1, h)); ks = fmaf(2.0f, k2, ks);
                float k3 = odef(fmaf(hsubh, k2, h)); ks = fmaf(2.0f, k3, ks);
                float k4 = odef(fmaf(hsub,  k3, h)); ks += k4;
                h = fmaf(h6, ks, h);
            }
        }
        {
            float t = fast_tanh(h);
            th_s[lane] = (__fp16)t;
            float o0 = 0.f, o1 = 0.f, o2 = 0.f, o3 = 0.f;
            const uint4* t4 = (const uint4*)th_s;
            #pragma unroll
            for (int q = 0; q < 8; ++q) {
                uint4 r = t4[q];
                o0 = fdot(r.x, wov[4*q+0], o0);
                o1 = fdot(r.y, wov[4*q+1], o1);
                o2 = fdot(r.z, wov[4*q+2], o2);
                o3 = fdot(r.w, wov[4*q+3], o3);
            }
            if (lane == 0) orow[SLEN - 1] = (o0 + o1) + (o2 + o3) + bo;
        }
    }
}

extern "C" void kernel_launch(void* const* d_in, const int* in_sizes, int n_in,
                              void* d_out, int out_size, void* d_ws, size_t ws_size,
                              hipStream_t stream) {
    const float* x     = (const float*)d_in[0];
    const float* W_in  = (const float*)d_in[1];
    const float* b_in  = (const float*)d_in[2];
    const float* W_hh  = (const float*)d_in[3];
    const float* W_ih  = (const float*)d_in[4];
    const float* bias  = (const float*)d_in[5];
    const float* tau   = (const float*)d_in[6];
    const float* W_out = (const float*)d_in[7];
    const float* b_out = (const float*)d_in[8];
    float* out = (float*)d_out;

    lnn_swap_kernel<<<512, 64, 0, stream>>>(x, W_in, b_in, W_hh, W_ih, bias,
                                            tau, W_out, b_out, out);
}